// Round 11
// baseline (317.662 us; speedup 1.0000x reference)
//
#include <hip/hip_runtime.h>
#include <math.h>

constexpr int BN = 64;
constexpr int CC = 128;
constexpr int LL = 400;
constexpr int DK = 16;
constexpr int KK = 7;
constexpr int CL = CC * LL;              // 51200
constexpr int NBCL = BN * CL;            // 3276800
constexpr float EPSV = 1e-5f;
constexpr float INV_N = 1.0f / (float)CL;
constexpr float BIGL = 1.4427e30f;

typedef __attribute__((ext_vector_type(8))) short bf16x8;
typedef __attribute__((ext_vector_type(4))) float f32x4;

#if defined(__has_builtin)
#if __has_builtin(__builtin_amdgcn_exp2f)
#define EXP2F(x) __builtin_amdgcn_exp2f(x)
#endif
#endif
#ifndef EXP2F
#define EXP2F(x) exp2f(x)
#endif

__device__ __forceinline__ short f2bf(float f) {        // RNE
  unsigned u = __builtin_bit_cast(unsigned, f);
  u = (u + 0x7fffu + ((u >> 16) & 1u)) >> 16;
  return (short)u;
}
__device__ __forceinline__ float bf2f(unsigned short u) {
  return __builtin_bit_cast(float, (unsigned)u << 16);
}
__device__ __forceinline__ unsigned pkbf(float hi, float lo) {  // truncate-pack
  return __builtin_amdgcn_perm(__builtin_bit_cast(unsigned, hi),
                               __builtin_bit_cast(unsigned, lo), 0x07060302u);
}

// ---------------------------------------------------------------------------
// 0) prep: weight frag-conversion + pos table + stats zero + folded conv bias
//    + precomputed additive attention mask (log2 domain, padded to 416)
// ---------------------------------------------------------------------------
__global__ __launch_bounds__(256) void prep_kernel(
    const float* __restrict__ pw_w, const float* __restrict__ wq,
    const float* __restrict__ wk, const float* __restrict__ wv,
    const float* __restrict__ wo, const float* __restrict__ fcw,
    const float* __restrict__ pw_b, const float* __restrict__ dw_b,
    const float* __restrict__ mask,
    unsigned short* __restrict__ wf, float* __restrict__ pose,
    float* __restrict__ stats, float* __restrict__ beff,
    float* __restrict__ maddb)
{
  int blk = blockIdx.x;
  if (blk < 576) {                       // 9 x 128x128 fp32 -> bf16 frag order
    int idx = blk * 256 + threadIdx.x;
    int mat = idx >> 14;
    int e = idx & 16383;
    const float* src;
    if (mat < 4)       src = pw_w + mat * 16384;
    else if (mat == 4) src = wq;
    else if (mat == 5) src = wk;
    else if (mat == 6) src = wv;
    else if (mat == 7) src = wo;
    else               src = fcw;
    int o = e >> 7, c = e & 127;
    int t = (o >> 4) * 4 + (c >> 5);
    int quad = (c >> 3) & 3, col = o & 15, j = c & 7;
    wf[mat * 16384 + t * 512 + (quad * 16 + col) * 8 + j] = (unsigned short)f2bf(src[e]);
  } else if (blk < 776) {                // pos table
    int idx = (blk - 576) * 256 + threadIdx.x;
    int c = idx / LL, l = idx - c * LL;
    float fc = (float)c;
    float freq, ph;
    if ((c & 1) == 0) { freq = powf(10000.f, -fc / (float)CC);        ph = 0.f; }
    else              { freq = -powf(10000.f, (1.f - fc) / (float)CC); ph = 1.5707963267948966f; }
    pose[idx] = sinf((float)l * freq + ph);
  } else if (blk == 776) {               // stats zero
    for (int i = threadIdx.x; i < 1024; i += 256) stats[i] = 0.f;
  } else if (blk == 777) {               // beff[i][o] = pw_b + PW @ dw_b
    for (int t = threadIdx.x; t < 512; t += 256) {
      int i = t >> 7, o = t & 127;
      float a = pw_b[t];
      const float* wrow = pw_w + (size_t)i * 16384 + o * 128;
      const float* db = dw_b + i * 128;
      for (int c2 = 0; c2 < 128; c2++) a += wrow[c2] * db[c2];
      beff[t] = a;
    }
  } else {                               // additive mask, 64 x 416
    int idx = (blk - 778) * 256 + threadIdx.x;   // 104 blocks
    int b = idx / 416, m = idx - b * 416;
    maddb[idx] = (m < LL) ? (mask[b * LL + m] - 1.f) * BIGL : -BIGL;
  }
}

// ---------------------------------------------------------------------------
// 1) res(bf16) = x + pose, accumulate LN stats on the ROUNDED values.
// ---------------------------------------------------------------------------
__global__ __launch_bounds__(256) void addpos_stats_kernel(
    const float* __restrict__ x, const float* __restrict__ pose,
    unsigned short* __restrict__ res, float* __restrict__ stats)
{
  int idx4 = blockIdx.x * 256 + threadIdx.x;    // 3200 blocks; 50 blocks per b
  int b = idx4 / (CL / 4);
  int cl4 = (idx4 - b * (CL / 4)) * 4;
  const float4 xv = *reinterpret_cast<const float4*>(&x[(size_t)idx4 * 4]);
  const float4 pv = *reinterpret_cast<const float4*>(&pose[cl4]);
  ushort4 h;
  h.x = (unsigned short)f2bf(xv.x + pv.x);
  h.y = (unsigned short)f2bf(xv.y + pv.y);
  h.z = (unsigned short)f2bf(xv.z + pv.z);
  h.w = (unsigned short)f2bf(xv.w + pv.w);
  *reinterpret_cast<ushort4*>(&res[(size_t)idx4 * 4]) = h;
  float v0 = bf2f(h.x), v1 = bf2f(h.y), v2 = bf2f(h.z), v3 = bf2f(h.w);
  float s1 = v0 + v1 + v2 + v3;
  float s2 = v0 * v0 + v1 * v1 + v2 * v2 + v3 * v3;
  #pragma unroll
  for (int off = 32; off > 0; off >>= 1) {
    s1 += __shfl_down(s1, off);
    s2 += __shfl_down(s2, off);
  }
  __shared__ float r1[4], r2[4];
  int wv = threadIdx.x >> 6, lane = threadIdx.x & 63;
  if (lane == 0) { r1[wv] = s1; r2[wv] = s2; }
  __syncthreads();
  if (threadIdx.x == 0) {
    atomicAdd(&stats[b * 2 + 0], r1[0] + r1[1] + r1[2] + r1[3]);
    atomicAdd(&stats[b * 2 + 1], r2[0] + r2[1] + r2[2] + r2[3]);
  }
}

// ---------------------------------------------------------------------------
// X staging (bf16 inputs) into fragment-ordered LDS tile, 8-wide groups.
// XMODE 0: + LN; XMODE 1: direct copy; XMODE 2: + LN + conv7
// ---------------------------------------------------------------------------
template<int XMODE>
__device__ __forceinline__ void stage_x(
    short* __restrict__ XsF, const unsigned short* __restrict__ Xb,
    int j0, const float* __restrict__ lng, const float* __restrict__ lnb,
    const float* __restrict__ dww, float mu, float rstd, int tid)
{
  for (int idx = tid; idx < 1024; idx += 512) {
    int c = idx >> 3;
    int l8 = (idx & 7) * 8;
    int col0 = j0 + l8;
    short hv[8];
    if (XMODE == 2) {
      const unsigned short* rp = Xb + c * LL;
      const float* gp = lng + c * LL;
      const float* bp = lnb + c * LL;
      float xn[16];
      #pragma unroll
      for (int g4 = 0; g4 < 4; g4++) {
        int p0 = col0 - 4 + g4 * 4;
        int pc = p0 < 0 ? 0 : (p0 > LL - 4 ? LL - 4 : p0);
        const ushort4 rv = *reinterpret_cast<const ushort4*>(&rp[pc]);
        const float4 gv = *reinterpret_cast<const float4*>(&gp[pc]);
        const float4 bv4 = *reinterpret_cast<const float4*>(&bp[pc]);
        float rr[4] = {bf2f(rv.x), bf2f(rv.y), bf2f(rv.z), bf2f(rv.w)};
        float gg[4] = {gv.x, gv.y, gv.z, gv.w};
        float bbv[4] = {bv4.x, bv4.y, bv4.z, bv4.w};
        #pragma unroll
        for (int e = 0; e < 4; e++) {
          int p = p0 + e;
          float v = (rr[e] - mu) * rstd * gg[e] + bbv[e];
          xn[g4 * 4 + e] = (p >= 0 && p < LL) ? v : 0.f;
        }
      }
      float w7[KK];
      #pragma unroll
      for (int j = 0; j < KK; j++) w7[j] = dww[c * KK + j];
      #pragma unroll
      for (int e = 0; e < 8; e++) {
        float a = 0.f;
        #pragma unroll
        for (int jj = 0; jj < KK; jj++) a += w7[jj] * xn[e + jj + 1];
        hv[e] = f2bf(a);
      }
    } else {
      bool valid = col0 < LL;               // LL % 8 == 0: all-or-nothing
      int col0c = valid ? col0 : 0;
      const unsigned short* xp = Xb + c * LL + col0c;
      const ushort4 u0 = *reinterpret_cast<const ushort4*>(&xp[0]);
      const ushort4 u1 = *reinterpret_cast<const ushort4*>(&xp[4]);
      unsigned short uu[8] = {u0.x, u0.y, u0.z, u0.w, u1.x, u1.y, u1.z, u1.w};
      if (XMODE == 1) {
        #pragma unroll
        for (int e = 0; e < 8; e++) hv[e] = valid ? (short)uu[e] : (short)0;
      } else {
        const float* gp = lng + c * LL + col0c;
        const float* bp = lnb + c * LL + col0c;
        const float4 g0 = *reinterpret_cast<const float4*>(&gp[0]);
        const float4 g1 = *reinterpret_cast<const float4*>(&gp[4]);
        const float4 b0 = *reinterpret_cast<const float4*>(&bp[0]);
        const float4 b1 = *reinterpret_cast<const float4*>(&bp[4]);
        float gg[8] = {g0.x, g0.y, g0.z, g0.w, g1.x, g1.y, g1.z, g1.w};
        float bbv[8] = {b0.x, b0.y, b0.z, b0.w, b1.x, b1.y, b1.z, b1.w};
        #pragma unroll
        for (int e = 0; e < 8; e++) {
          float v = (bf2f(uu[e]) - mu) * rstd * gg[e] + bbv[e];
          hv[e] = valid ? f2bf(v) : (short)0;
        }
      }
    }
    int t = (l8 >> 4) * 4 + (c >> 5);
    int quad = (c >> 3) & 3;
    int j = c & 7;
    int base = t * 512 + quad * 128 + j;
    int colb = l8 & 15;
    #pragma unroll
    for (int e = 0; e < 8; e++) XsF[base + (colb + e) * 8] = hv[e];
  }
}

// ---------------------------------------------------------------------------
// 2) MFMA GEMM (W fragments loaded straight from global wf); bf16 resid;
//    OMODE 0: fp32 linear; 1: bf16 linear; 2: bf16 transposed (b,h,l,d)
// ---------------------------------------------------------------------------
template<int XMODE, int OMODE, bool RELU, bool ADDRES, bool STATS>
__device__ __forceinline__ void gemm_body(
    const unsigned short* __restrict__ Wf, const unsigned short* __restrict__ Xv,
    const float* __restrict__ bias, const unsigned short* __restrict__ resid,
    const float* __restrict__ lng, const float* __restrict__ lnb,
    const float* __restrict__ dww,
    const float* __restrict__ statsIn, float* __restrict__ statsOut,
    void* __restrict__ Yv)
{
  __shared__ short XsF[16 * 512];
  __shared__ float red[16];
  int tid = threadIdx.x;
  int bb = blockIdx.y;
  int j0 = blockIdx.x * 64;
  int w = tid >> 6, lane = tid & 63;
  bf16x8 af[4];
  #pragma unroll
  for (int kt = 0; kt < 4; kt++)
    af[kt] = *reinterpret_cast<const bf16x8*>(&Wf[(w * 4 + kt) * 512 + lane * 8]);
  float mu = 0.f, rstd = 0.f;
  if (XMODE != 1) {
    float s1 = statsIn[bb * 2 + 0], s2 = statsIn[bb * 2 + 1];
    mu = s1 * INV_N;
    rstd = rsqrtf(s2 * INV_N - mu * mu + EPSV);
  }
  stage_x<XMODE>(XsF, Xv + (size_t)bb * CL, j0, lng, lnb, dww, mu, rstd, tid);
  __syncthreads();
  int col = lane & 15, quad = lane >> 4;
  f32x4 acc[4];
  #pragma unroll
  for (int lf = 0; lf < 4; lf++) acc[lf] = (f32x4){0.f, 0.f, 0.f, 0.f};
  #pragma unroll
  for (int kt = 0; kt < 4; kt++) {
    #pragma unroll
    for (int lf = 0; lf < 4; lf++) {
      bf16x8 bx = *reinterpret_cast<const bf16x8*>(&XsF[(lf * 4 + kt) * 512 + lane * 8]);
      acc[lf] = __builtin_amdgcn_mfma_f32_16x16x32_bf16(af[kt], bx, acc[lf], 0, 0, 0);
    }
  }
  int obase = w * 16;
  float bv[4];
  #pragma unroll
  for (int r = 0; r < 4; r++) bv[r] = bias[obase + quad * 4 + r];
  float lsum = 0.f, lsq = 0.f;
  #pragma unroll
  for (int lf = 0; lf < 4; lf++) {
    if (j0 + lf * 16 < LL) {
      int l = j0 + lf * 16 + col;
      if (OMODE == 2) {
        short4 hv4 = {f2bf(acc[lf][0] + bv[0]), f2bf(acc[lf][1] + bv[1]),
                      f2bf(acc[lf][2] + bv[2]), f2bf(acc[lf][3] + bv[3])};
        *reinterpret_cast<short4*>(
            &((unsigned short*)Yv)[(((size_t)bb * 8 + w) * LL + l) * 16 + quad * 4]) = hv4;
      } else {
        #pragma unroll
        for (int r = 0; r < 4; r++) {
          float v = acc[lf][r] + bv[r];
          if (RELU) v = fmaxf(v, 0.f);
          size_t oidx = (size_t)bb * CL + (size_t)(obase + quad * 4 + r) * LL + l;
          if (ADDRES) v += bf2f(resid[oidx]);
          if (OMODE == 1) {
            unsigned short hb = (unsigned short)f2bf(v);
            ((unsigned short*)Yv)[oidx] = hb;
            if (STATS) { float vf = bf2f(hb); lsum += vf; lsq += vf * vf; }
          } else {
            ((float*)Yv)[oidx] = v;
            if (STATS) { lsum += v; lsq += v * v; }
          }
        }
      }
    }
  }
  if (STATS) {
    #pragma unroll
    for (int off = 32; off > 0; off >>= 1) {
      lsum += __shfl_down(lsum, off);
      lsq  += __shfl_down(lsq, off);
    }
    if (lane == 0) { red[w * 2] = lsum; red[w * 2 + 1] = lsq; }
    __syncthreads();
    if (tid == 0) {
      float a = 0.f, b2 = 0.f;
      #pragma unroll
      for (int w2 = 0; w2 < 8; w2++) { a += red[w2 * 2]; b2 += red[w2 * 2 + 1]; }
      atomicAdd(&statsOut[bb * 2 + 0], a);
      atomicAdd(&statsOut[bb * 2 + 1], b2);
    }
  }
}

template<int XMODE, int OMODE, bool RELU, bool ADDRES, bool STATS>
__global__ __launch_bounds__(512) void gemmM(
    const unsigned short* __restrict__ Wf, const unsigned short* __restrict__ X,
    const float* __restrict__ bias, const unsigned short* __restrict__ resid,
    const float* __restrict__ lng, const float* __restrict__ lnb,
    const float* __restrict__ dww,
    const float* __restrict__ statsIn, float* __restrict__ statsOut,
    void* __restrict__ Y)
{
  gemm_body<XMODE, OMODE, RELU, ADDRES, STATS>(
      Wf, X, bias, resid, lng, lnb, dww, statsIn, statsOut, Y);
}

// QKV: z-parallel (1344 blocks). Q,K -> (b,h,l,d) bf16; V -> (b,c,l) bf16.
__global__ __launch_bounds__(512) void qkv_kernel(
    const unsigned short* __restrict__ wf,
    const float* __restrict__ bq, const float* __restrict__ bk, const float* __restrict__ bv,
    const unsigned short* __restrict__ X,
    const float* __restrict__ lng, const float* __restrict__ lnb,
    const float* __restrict__ statsIn,
    unsigned short* __restrict__ qt, unsigned short* __restrict__ kt,
    unsigned short* __restrict__ vb)
{
  if (blockIdx.z == 0)
    gemm_body<0, 2, false, false, false>(wf + 4 * 16384, X, bq, nullptr, lng, lnb,
                                         nullptr, statsIn, nullptr, qt);
  else if (blockIdx.z == 1)
    gemm_body<0, 2, false, false, false>(wf + 5 * 16384, X, bk, nullptr, lng, lnb,
                                         nullptr, statsIn, nullptr, kt);
  else
    gemm_body<0, 1, false, false, false>(wf + 6 * 16384, X, bv, nullptr, lng, lnb,
                                         nullptr, statsIn, nullptr, vb);
}

// ---------------------------------------------------------------------------
// 3) attention: 4 waves/block = 2 l-tiles x 2 m-halves (static-max softmax
//    partials combine additively). 16-row f-level double-buffered P per wave.
//    One barrier to merge halves via LDS.
// ---------------------------------------------------------------------------
__global__ __launch_bounds__(256, 8) void attn_kernel(
    const unsigned short* __restrict__ qt, const unsigned short* __restrict__ kt,
    const unsigned short* __restrict__ vb, const float* __restrict__ maddb,
    unsigned short* __restrict__ ao)
{
  __shared__ short Pl[4][2][640];           // 10240 B: per-wave f-level dbuf
  __shared__ float Mg[2][64][20];           // 10240 B: merge of[16]+psum[4]
  int bh = blockIdx.x;
  int b = bh >> 3, h = bh & 7;
  int w = threadIdx.x >> 6, lane = threadIdx.x & 63;
  int pair = w >> 1, half = w & 1;
  int tile = blockIdx.y * 2 + pair;
  bool live = tile < 7;
  int tile_c = live ? tile : 6;
  int col = lane & 15, quad = lane >> 4;
  int l0 = tile_c * 64;
  size_t trow = ((size_t)b * 8 + h) * LL;
  size_t base = ((size_t)b * CC + h * DK) * LL;
  const unsigned short* qp = qt + trow * 16;
  const unsigned short* kp = kt + trow * 16;
  const unsigned short* vp = vb + base;
  const float* mb = maddb + (size_t)b * 416;

  bf16x8 qf[4];
  #pragma unroll
  for (int f = 0; f < 4; f++) {
    bf16x8 v = {};
    if (quad < 2) {
      int l = l0 + f * 16 + col; int lc = l < LL ? l : LL - 1;
      v = *reinterpret_cast<const bf16x8*>(&qp[lc * 16 + quad * 8]);
    }
    qf[f] = v;
  }
  f32x4 of[4];
  float psum[4];
  #pragma unroll
  for (int f = 0; f < 4; f++) {
    of[f] = (f32x4){0.f, 0.f, 0.f, 0.f};
    psum[f] = 0.f;
  }
  const float scale2 = 0.08838834764831845f * 1.4426950408889634f;  // /sqrt(128)*log2e

  int mstart = half ? 224 : 0;
  int mend   = half ? 416 : 224;            // 6 / 7 steps of 32
  for (int m0 = mstart; m0 < mend; m0 += 32) {
    bf16x8 kf0 = {}, kf1 = {};
    if (quad < 2) {
      int mc0 = m0 + col < LL ? m0 + col : LL - 1;
      int mc1 = m0 + 16 + col < LL ? m0 + 16 + col : LL - 1;
      kf0 = *reinterpret_cast<const bf16x8*>(&kp[mc0 * 16 + quad * 8]);
      kf1 = *reinterpret_cast<const bf16x8*>(&kp[mc1 * 16 + quad * 8]);
    }
    bf16x8 vf;
    {
      int ms = m0 + quad * 8; if (ms > LL - 8) ms = LL - 8;
      vf = *reinterpret_cast<const bf16x8*>(&vp[col * LL + ms]);
    }
    const float4 a4 = *reinterpret_cast<const float4*>(&mb[m0 + quad * 4]);
    const float4 b4 = *reinterpret_cast<const float4*>(&mb[m0 + 16 + quad * 4]);
    float madd[8] = {a4.x, a4.y, a4.z, a4.w, b4.x, b4.y, b4.z, b4.w};
    #pragma unroll
    for (int f = 0; f < 4; f++) {
      f32x4 z = {0.f, 0.f, 0.f, 0.f};
      f32x4 s0 = __builtin_amdgcn_mfma_f32_16x16x32_bf16(kf0, qf[f], z, 0, 0, 0);
      f32x4 s1 = __builtin_amdgcn_mfma_f32_16x16x32_bf16(kf1, qf[f], z, 0, 0, 0);
      float p[8];
      #pragma unroll
      for (int r = 0; r < 4; r++) {
        p[r]     = EXP2F(s0[r] * scale2 + madd[r]);
        p[4 + r] = EXP2F(s1[r] * scale2 + madd[4 + r]);
      }
      float ps = 0.f;
      #pragma unroll
      for (int i = 0; i < 8; i++) ps += p[i];
      psum[f] += ps;
      short* row = &Pl[w][f & 1][col * 40];
      short4 h0 = __builtin_bit_cast(short4, make_uint2(pkbf(p[1], p[0]), pkbf(p[3], p[2])));
      short4 h1 = __builtin_bit_cast(short4, make_uint2(pkbf(p[5], p[4]), pkbf(p[7], p[6])));
      *reinterpret_cast<short4*>(&row[quad * 4])      = h0;
      *reinterpret_cast<short4*>(&row[16 + quad * 4]) = h1;
      bf16x8 pf = *reinterpret_cast<const bf16x8*>(&Pl[w][f & 1][col * 40 + quad * 8]);
      of[f] = __builtin_amdgcn_mfma_f32_16x16x32_bf16(vf, pf, of[f], 0, 0, 0);
    }
  }
  // merge halves: half-1 waves publish partials, half-0 waves combine
  if (half == 1) {
    float* mg = &Mg[pair][lane][0];
    #pragma unroll
    for (int f = 0; f < 4; f++) {
      #pragma unroll
      for (int r = 0; r < 4; r++) mg[f * 4 + r] = of[f][r];
      mg[16 + f] = psum[f];
    }
  }
  __syncthreads();
  if (half == 0 && live) {
    const float* mg = &Mg[pair][lane][0];
    #pragma unroll
    for (int f = 0; f < 4; f++) {
      #pragma unroll
      for (int r = 0; r < 4; r++) of[f][r] += mg[f * 4 + r];
      psum[f] += mg[16 + f];
    }
    #pragma unroll
    for (int f = 0; f < 4; f++) {
      float s = psum[f];
      s += __shfl_xor(s, 16);
      s += __shfl_xor(s, 32);
      float inv = 1.f / s;
      int lf = l0 + f * 16;
      if (lf < LL) {
        #pragma unroll
        for (int r = 0; r < 4; r++)
          ao[base + (size_t)(quad * 4 + r) * LL + lf + col] =
              (unsigned short)f2bf(of[f][r] * inv);
      }
    }
  }
}

// ---------------------------------------------------------------------------
extern "C" void kernel_launch(void* const* d_in, const int* in_sizes, int n_in,
                              void* d_out, int out_size, void* d_ws, size_t ws_size,
                              hipStream_t stream) {
  const float* x    = (const float*)d_in[0];
  const float* mask = (const float*)d_in[1];
  const float* dw_w = (const float*)d_in[2];
  const float* dw_b = (const float*)d_in[3];
  const float* pw_w = (const float*)d_in[4];
  const float* pw_b = (const float*)d_in[5];
  const float* wq   = (const float*)d_in[6];
  const float* bq   = (const float*)d_in[7];
  const float* wk   = (const float*)d_in[8];
  const float* bk   = (const float*)d_in[9];
  const float* wvp  = (const float*)d_in[10];
  const float* bv   = (const float*)d_in[11];
  const float* wo   = (const float*)d_in[12];
  const float* bo   = (const float*)d_in[13];
  const float* fcw  = (const float*)d_in[14];
  const float* fcb  = (const float*)d_in[15];
  const float* lng  = (const float*)d_in[16];
  const float* lnb  = (const float*)d_in[17];
  float* out = (float*)d_out;
  float* ws  = (float*)d_ws;

  float* stats = ws;                                    // 1024 f
  float* pose  = ws + 1024;                             // 51200 f
  float* beff  = pose + 51200;                          // 512 f
  float* maddb = beff + 512;                            // 64*416 f
  unsigned short* wf = (unsigned short*)(maddb + 64 * 416); // 9*16384 bf16
  unsigned short* r0 = wf + 9 * 16384;                  // NBCL bf16 each:
  unsigned short* r1 = r0 + NBCL;
  unsigned short* qt = r1 + NBCL;
  unsigned short* kt = qt + NBCL;
  unsigned short* vbf = kt + NBCL;
  unsigned short* tb = vbf + NBCL;

  prep_kernel<<<882, 256, 0, stream>>>(pw_w, wq, wk, wvp, wo, fcw, pw_b, dw_b,
                                       mask, wf, pose, stats, beff, maddb);
  addpos_stats_kernel<<<3200, 256, 0, stream>>>(x, pose, r0, stats);

  // conv layers, ping-pong r0 <-> r1 (no in-place halo race)
  unsigned short* rin = r0;
  unsigned short* rout = r1;
  for (int i = 0; i < 4; i++) {
    gemmM<2, 1, true, true, true><<<dim3(7, BN), 512, 0, stream>>>(
        wf + i * 16384, rin, beff + i * CC, rin, lng, lnb,
        dw_w + i * CC * KK, stats + i * 128, stats + (i + 1) * 128, rout);
    unsigned short* t = rin; rin = rout; rout = t;
  }
  // after 4 layers: rin = r0 (current residual stream)
  qkv_kernel<<<dim3(7, BN, 3), 512, 0, stream>>>(
      wf, bq, bk, bv, rin, lng, lnb, stats + 4 * 128, qt, kt, vbf);
  attn_kernel<<<dim3(512, 4), 256, 0, stream>>>(qt, kt, vbf, maddb, tb);
  // WO projection + residual -> rout(bf16), stats5
  gemmM<1, 1, false, true, true><<<dim3(7, BN), 512, 0, stream>>>(
      wf + 7 * 16384, tb, bo, rin, nullptr, nullptr, nullptr,
      nullptr, stats + 5 * 128, rout);
  // FC (LN on load) + ReLU + residual -> d_out (fp32)
  gemmM<0, 0, true, true, false><<<dim3(7, BN), 512, 0, stream>>>(
      wf + 8 * 16384, rout, fcb, rout, lng, lnb, nullptr,
      stats + 5 * 128, nullptr, out);
}

// Round 12
// 244.763 us; speedup vs baseline: 1.2978x; 1.2978x over previous
//
#include <hip/hip_runtime.h>
#include <math.h>

constexpr int BN = 64;
constexpr int CC = 128;
constexpr int LL = 400;
constexpr int DK = 16;
constexpr int KK = 7;
constexpr int CL = CC * LL;              // 51200
constexpr int NBCL = BN * CL;            // 3276800
constexpr float EPSV = 1e-5f;
constexpr float INV_N = 1.0f / (float)CL;
constexpr float BIGL = 1.4427e30f;

typedef __attribute__((ext_vector_type(8))) short bf16x8;
typedef __attribute__((ext_vector_type(4))) float f32x4;

#if defined(__has_builtin)
#if __has_builtin(__builtin_amdgcn_exp2f)
#define EXP2F(x) __builtin_amdgcn_exp2f(x)
#endif
#endif
#ifndef EXP2F
#define EXP2F(x) exp2f(x)
#endif

__device__ __forceinline__ short f2bf(float f) {        // RNE
  unsigned u = __builtin_bit_cast(unsigned, f);
  u = (u + 0x7fffu + ((u >> 16) & 1u)) >> 16;
  return (short)u;
}
__device__ __forceinline__ float bf2f(unsigned short u) {
  return __builtin_bit_cast(float, (unsigned)u << 16);
}
__device__ __forceinline__ unsigned pkbf(float hi, float lo) {  // truncate-pack
  return __builtin_amdgcn_perm(__builtin_bit_cast(unsigned, hi),
                               __builtin_bit_cast(unsigned, lo), 0x07060302u);
}

// ---------------------------------------------------------------------------
// 0) prep: weight frag-conversion + pos table + stats zero + folded conv bias
//    + precomputed additive attention mask (log2 domain, padded to 416)
// ---------------------------------------------------------------------------
__global__ __launch_bounds__(256) void prep_kernel(
    const float* __restrict__ pw_w, const float* __restrict__ wq,
    const float* __restrict__ wk, const float* __restrict__ wv,
    const float* __restrict__ wo, const float* __restrict__ fcw,
    const float* __restrict__ pw_b, const float* __restrict__ dw_b,
    const float* __restrict__ mask,
    unsigned short* __restrict__ wf, float* __restrict__ pose,
    float* __restrict__ stats, float* __restrict__ beff,
    float* __restrict__ maddb)
{
  int blk = blockIdx.x;
  if (blk < 576) {                       // 9 x 128x128 fp32 -> bf16 frag order
    int idx = blk * 256 + threadIdx.x;
    int mat = idx >> 14;
    int e = idx & 16383;
    const float* src;
    if (mat < 4)       src = pw_w + mat * 16384;
    else if (mat == 4) src = wq;
    else if (mat == 5) src = wk;
    else if (mat == 6) src = wv;
    else if (mat == 7) src = wo;
    else               src = fcw;
    int o = e >> 7, c = e & 127;
    int t = (o >> 4) * 4 + (c >> 5);
    int quad = (c >> 3) & 3, col = o & 15, j = c & 7;
    wf[mat * 16384 + t * 512 + (quad * 16 + col) * 8 + j] = (unsigned short)f2bf(src[e]);
  } else if (blk < 776) {                // pos table
    int idx = (blk - 576) * 256 + threadIdx.x;
    int c = idx / LL, l = idx - c * LL;
    float fc = (float)c;
    float freq, ph;
    if ((c & 1) == 0) { freq = powf(10000.f, -fc / (float)CC);        ph = 0.f; }
    else              { freq = -powf(10000.f, (1.f - fc) / (float)CC); ph = 1.5707963267948966f; }
    pose[idx] = sinf((float)l * freq + ph);
  } else if (blk == 776) {               // stats zero
    for (int i = threadIdx.x; i < 1024; i += 256) stats[i] = 0.f;
  } else if (blk == 777) {               // beff[i][o] = pw_b + PW @ dw_b
    for (int t = threadIdx.x; t < 512; t += 256) {
      int i = t >> 7, o = t & 127;
      float a = pw_b[t];
      const float* wrow = pw_w + (size_t)i * 16384 + o * 128;
      const float* db = dw_b + i * 128;
      for (int c2 = 0; c2 < 128; c2++) a += wrow[c2] * db[c2];
      beff[t] = a;
    }
  } else {                               // additive mask, 64 x 416
    int idx = (blk - 778) * 256 + threadIdx.x;   // 104 blocks
    int b = idx / 416, m = idx - b * 416;
    maddb[idx] = (m < LL) ? (mask[b * LL + m] - 1.f) * BIGL : -BIGL;
  }
}

// ---------------------------------------------------------------------------
// 1) res(bf16) = x + pose, accumulate LN stats on the ROUNDED values.
// ---------------------------------------------------------------------------
__global__ __launch_bounds__(256) void addpos_stats_kernel(
    const float* __restrict__ x, const float* __restrict__ pose,
    unsigned short* __restrict__ res, float* __restrict__ stats)
{
  int idx4 = blockIdx.x * 256 + threadIdx.x;    // 3200 blocks; 50 blocks per b
  int b = idx4 / (CL / 4);
  int cl4 = (idx4 - b * (CL / 4)) * 4;
  const float4 xv = *reinterpret_cast<const float4*>(&x[(size_t)idx4 * 4]);
  const float4 pv = *reinterpret_cast<const float4*>(&pose[cl4]);
  ushort4 h;
  h.x = (unsigned short)f2bf(xv.x + pv.x);
  h.y = (unsigned short)f2bf(xv.y + pv.y);
  h.z = (unsigned short)f2bf(xv.z + pv.z);
  h.w = (unsigned short)f2bf(xv.w + pv.w);
  *reinterpret_cast<ushort4*>(&res[(size_t)idx4 * 4]) = h;
  float v0 = bf2f(h.x), v1 = bf2f(h.y), v2 = bf2f(h.z), v3 = bf2f(h.w);
  float s1 = v0 + v1 + v2 + v3;
  float s2 = v0 * v0 + v1 * v1 + v2 * v2 + v3 * v3;
  #pragma unroll
  for (int off = 32; off > 0; off >>= 1) {
    s1 += __shfl_down(s1, off);
    s2 += __shfl_down(s2, off);
  }
  __shared__ float r1[4], r2[4];
  int wv = threadIdx.x >> 6, lane = threadIdx.x & 63;
  if (lane == 0) { r1[wv] = s1; r2[wv] = s2; }
  __syncthreads();
  if (threadIdx.x == 0) {
    atomicAdd(&stats[b * 2 + 0], r1[0] + r1[1] + r1[2] + r1[3]);
    atomicAdd(&stats[b * 2 + 1], r2[0] + r2[1] + r2[2] + r2[3]);
  }
}

// ---------------------------------------------------------------------------
// X staging (bf16 inputs) into fragment-ordered LDS tile, 8-wide groups.
// XMODE 0: + LN; XMODE 1: direct copy; XMODE 2: + LN + conv7
// ---------------------------------------------------------------------------
template<int XMODE>
__device__ __forceinline__ void stage_x(
    short* __restrict__ XsF, const unsigned short* __restrict__ Xb,
    int j0, const float* __restrict__ lng, const float* __restrict__ lnb,
    const float* __restrict__ dww, float mu, float rstd, int tid)
{
  for (int idx = tid; idx < 1024; idx += 512) {
    int c = idx >> 3;
    int l8 = (idx & 7) * 8;
    int col0 = j0 + l8;
    short hv[8];
    if (XMODE == 2) {
      const unsigned short* rp = Xb + c * LL;
      const float* gp = lng + c * LL;
      const float* bp = lnb + c * LL;
      float xn[16];
      #pragma unroll
      for (int g4 = 0; g4 < 4; g4++) {
        int p0 = col0 - 4 + g4 * 4;
        int pc = p0 < 0 ? 0 : (p0 > LL - 4 ? LL - 4 : p0);
        const ushort4 rv = *reinterpret_cast<const ushort4*>(&rp[pc]);
        const float4 gv = *reinterpret_cast<const float4*>(&gp[pc]);
        const float4 bv4 = *reinterpret_cast<const float4*>(&bp[pc]);
        float rr[4] = {bf2f(rv.x), bf2f(rv.y), bf2f(rv.z), bf2f(rv.w)};
        float gg[4] = {gv.x, gv.y, gv.z, gv.w};
        float bbv[4] = {bv4.x, bv4.y, bv4.z, bv4.w};
        #pragma unroll
        for (int e = 0; e < 4; e++) {
          int p = p0 + e;
          float v = (rr[e] - mu) * rstd * gg[e] + bbv[e];
          xn[g4 * 4 + e] = (p >= 0 && p < LL) ? v : 0.f;
        }
      }
      float w7[KK];
      #pragma unroll
      for (int j = 0; j < KK; j++) w7[j] = dww[c * KK + j];
      #pragma unroll
      for (int e = 0; e < 8; e++) {
        float a = 0.f;
        #pragma unroll
        for (int jj = 0; jj < KK; jj++) a += w7[jj] * xn[e + jj + 1];
        hv[e] = f2bf(a);
      }
    } else {
      bool valid = col0 < LL;               // LL % 8 == 0: all-or-nothing
      int col0c = valid ? col0 : 0;
      const unsigned short* xp = Xb + c * LL + col0c;
      const ushort4 u0 = *reinterpret_cast<const ushort4*>(&xp[0]);
      const ushort4 u1 = *reinterpret_cast<const ushort4*>(&xp[4]);
      unsigned short uu[8] = {u0.x, u0.y, u0.z, u0.w, u1.x, u1.y, u1.z, u1.w};
      if (XMODE == 1) {
        #pragma unroll
        for (int e = 0; e < 8; e++) hv[e] = valid ? (short)uu[e] : (short)0;
      } else {
        const float* gp = lng + c * LL + col0c;
        const float* bp = lnb + c * LL + col0c;
        const float4 g0 = *reinterpret_cast<const float4*>(&gp[0]);
        const float4 g1 = *reinterpret_cast<const float4*>(&gp[4]);
        const float4 b0 = *reinterpret_cast<const float4*>(&bp[0]);
        const float4 b1 = *reinterpret_cast<const float4*>(&bp[4]);
        float gg[8] = {g0.x, g0.y, g0.z, g0.w, g1.x, g1.y, g1.z, g1.w};
        float bbv[8] = {b0.x, b0.y, b0.z, b0.w, b1.x, b1.y, b1.z, b1.w};
        #pragma unroll
        for (int e = 0; e < 8; e++) {
          float v = (bf2f(uu[e]) - mu) * rstd * gg[e] + bbv[e];
          hv[e] = valid ? f2bf(v) : (short)0;
        }
      }
    }
    int t = (l8 >> 4) * 4 + (c >> 5);
    int quad = (c >> 3) & 3;
    int j = c & 7;
    int base = t * 512 + quad * 128 + j;
    int colb = l8 & 15;
    #pragma unroll
    for (int e = 0; e < 8; e++) XsF[base + (colb + e) * 8] = hv[e];
  }
}

// ---------------------------------------------------------------------------
// 2) MFMA GEMM (W fragments loaded straight from global wf); bf16 resid;
//    OMODE 0: fp32 linear; 1: bf16 linear; 2: bf16 transposed (b,h,l,d)
// ---------------------------------------------------------------------------
template<int XMODE, int OMODE, bool RELU, bool ADDRES, bool STATS>
__device__ __forceinline__ void gemm_body(
    const unsigned short* __restrict__ Wf, const unsigned short* __restrict__ Xv,
    const float* __restrict__ bias, const unsigned short* __restrict__ resid,
    const float* __restrict__ lng, const float* __restrict__ lnb,
    const float* __restrict__ dww,
    const float* __restrict__ statsIn, float* __restrict__ statsOut,
    void* __restrict__ Yv)
{
  __shared__ short XsF[16 * 512];
  __shared__ float red[16];
  int tid = threadIdx.x;
  int bb = blockIdx.y;
  int j0 = blockIdx.x * 64;
  int w = tid >> 6, lane = tid & 63;
  bf16x8 af[4];
  #pragma unroll
  for (int kt = 0; kt < 4; kt++)
    af[kt] = *reinterpret_cast<const bf16x8*>(&Wf[(w * 4 + kt) * 512 + lane * 8]);
  float mu = 0.f, rstd = 0.f;
  if (XMODE != 1) {
    float s1 = statsIn[bb * 2 + 0], s2 = statsIn[bb * 2 + 1];
    mu = s1 * INV_N;
    rstd = rsqrtf(s2 * INV_N - mu * mu + EPSV);
  }
  stage_x<XMODE>(XsF, Xv + (size_t)bb * CL, j0, lng, lnb, dww, mu, rstd, tid);
  __syncthreads();
  int col = lane & 15, quad = lane >> 4;
  f32x4 acc[4];
  #pragma unroll
  for (int lf = 0; lf < 4; lf++) acc[lf] = (f32x4){0.f, 0.f, 0.f, 0.f};
  #pragma unroll
  for (int kt = 0; kt < 4; kt++) {
    #pragma unroll
    for (int lf = 0; lf < 4; lf++) {
      bf16x8 bx = *reinterpret_cast<const bf16x8*>(&XsF[(lf * 4 + kt) * 512 + lane * 8]);
      acc[lf] = __builtin_amdgcn_mfma_f32_16x16x32_bf16(af[kt], bx, acc[lf], 0, 0, 0);
    }
  }
  int obase = w * 16;
  float bv[4];
  #pragma unroll
  for (int r = 0; r < 4; r++) bv[r] = bias[obase + quad * 4 + r];
  float lsum = 0.f, lsq = 0.f;
  #pragma unroll
  for (int lf = 0; lf < 4; lf++) {
    if (j0 + lf * 16 < LL) {
      int l = j0 + lf * 16 + col;
      if (OMODE == 2) {
        short4 hv4 = {f2bf(acc[lf][0] + bv[0]), f2bf(acc[lf][1] + bv[1]),
                      f2bf(acc[lf][2] + bv[2]), f2bf(acc[lf][3] + bv[3])};
        *reinterpret_cast<short4*>(
            &((unsigned short*)Yv)[(((size_t)bb * 8 + w) * LL + l) * 16 + quad * 4]) = hv4;
      } else {
        #pragma unroll
        for (int r = 0; r < 4; r++) {
          float v = acc[lf][r] + bv[r];
          if (RELU) v = fmaxf(v, 0.f);
          size_t oidx = (size_t)bb * CL + (size_t)(obase + quad * 4 + r) * LL + l;
          if (ADDRES) v += bf2f(resid[oidx]);
          if (OMODE == 1) {
            unsigned short hb = (unsigned short)f2bf(v);
            ((unsigned short*)Yv)[oidx] = hb;
            if (STATS) { float vf = bf2f(hb); lsum += vf; lsq += vf * vf; }
          } else {
            ((float*)Yv)[oidx] = v;
            if (STATS) { lsum += v; lsq += v * v; }
          }
        }
      }
    }
  }
  if (STATS) {
    #pragma unroll
    for (int off = 32; off > 0; off >>= 1) {
      lsum += __shfl_down(lsum, off);
      lsq  += __shfl_down(lsq, off);
    }
    if (lane == 0) { red[w * 2] = lsum; red[w * 2 + 1] = lsq; }
    __syncthreads();
    if (tid == 0) {
      float a = 0.f, b2 = 0.f;
      #pragma unroll
      for (int w2 = 0; w2 < 8; w2++) { a += red[w2 * 2]; b2 += red[w2 * 2 + 1]; }
      atomicAdd(&statsOut[bb * 2 + 0], a);
      atomicAdd(&statsOut[bb * 2 + 1], b2);
    }
  }
}

template<int XMODE, int OMODE, bool RELU, bool ADDRES, bool STATS>
__global__ __launch_bounds__(512) void gemmM(
    const unsigned short* __restrict__ Wf, const unsigned short* __restrict__ X,
    const float* __restrict__ bias, const unsigned short* __restrict__ resid,
    const float* __restrict__ lng, const float* __restrict__ lnb,
    const float* __restrict__ dww,
    const float* __restrict__ statsIn, float* __restrict__ statsOut,
    void* __restrict__ Y)
{
  gemm_body<XMODE, OMODE, RELU, ADDRES, STATS>(
      Wf, X, bias, resid, lng, lnb, dww, statsIn, statsOut, Y);
}

// QKV: z-parallel (1344 blocks). Q,K -> (b,h,l,d) bf16; V -> (b,c,l) bf16.
__global__ __launch_bounds__(512) void qkv_kernel(
    const unsigned short* __restrict__ wf,
    const float* __restrict__ bq, const float* __restrict__ bk, const float* __restrict__ bv,
    const unsigned short* __restrict__ X,
    const float* __restrict__ lng, const float* __restrict__ lnb,
    const float* __restrict__ statsIn,
    unsigned short* __restrict__ qt, unsigned short* __restrict__ kt,
    unsigned short* __restrict__ vb)
{
  if (blockIdx.z == 0)
    gemm_body<0, 2, false, false, false>(wf + 4 * 16384, X, bq, nullptr, lng, lnb,
                                         nullptr, statsIn, nullptr, qt);
  else if (blockIdx.z == 1)
    gemm_body<0, 2, false, false, false>(wf + 5 * 16384, X, bk, nullptr, lng, lnb,
                                         nullptr, statsIn, nullptr, kt);
  else
    gemm_body<0, 1, false, false, false>(wf + 6 * 16384, X, bv, nullptr, lng, lnb,
                                         nullptr, statsIn, nullptr, vb);
}

// ---------------------------------------------------------------------------
// 3) attention: 4 waves/block = 2 l-tiles x 2 m-halves (static-max softmax
//    partials combine additively). 16-row f-level double-buffered P per wave.
//    One barrier to merge halves via LDS. launch_bounds(256,4): VGPR cap 128
//    (the (256,8) variant forced a 64-VGPR cap -> full scratch spill, 94 us).
// ---------------------------------------------------------------------------
__global__ __launch_bounds__(256, 4) void attn_kernel(
    const unsigned short* __restrict__ qt, const unsigned short* __restrict__ kt,
    const unsigned short* __restrict__ vb, const float* __restrict__ maddb,
    unsigned short* __restrict__ ao)
{
  __shared__ short Pl[4][2][640];           // 10240 B: per-wave f-level dbuf
  __shared__ float Mg[2][64][20];           // 10240 B: merge of[16]+psum[4]
  int bh = blockIdx.x;
  int b = bh >> 3, h = bh & 7;
  int w = threadIdx.x >> 6, lane = threadIdx.x & 63;
  int pair = w >> 1, half = w & 1;
  int tile = blockIdx.y * 2 + pair;
  bool live = tile < 7;
  int tile_c = live ? tile : 6;
  int col = lane & 15, quad = lane >> 4;
  int l0 = tile_c * 64;
  size_t trow = ((size_t)b * 8 + h) * LL;
  size_t base = ((size_t)b * CC + h * DK) * LL;
  const unsigned short* qp = qt + trow * 16;
  const unsigned short* kp = kt + trow * 16;
  const unsigned short* vp = vb + base;
  const float* mb = maddb + (size_t)b * 416;

  bf16x8 qf[4];
  #pragma unroll
  for (int f = 0; f < 4; f++) {
    bf16x8 v = {};
    if (quad < 2) {
      int l = l0 + f * 16 + col; int lc = l < LL ? l : LL - 1;
      v = *reinterpret_cast<const bf16x8*>(&qp[lc * 16 + quad * 8]);
    }
    qf[f] = v;
  }
  f32x4 of[4];
  float psum[4];
  #pragma unroll
  for (int f = 0; f < 4; f++) {
    of[f] = (f32x4){0.f, 0.f, 0.f, 0.f};
    psum[f] = 0.f;
  }
  const float scale2 = 0.08838834764831845f * 1.4426950408889634f;  // /sqrt(128)*log2e

  int mstart = half ? 224 : 0;
  int mend   = half ? 416 : 224;            // 6 / 7 steps of 32
  for (int m0 = mstart; m0 < mend; m0 += 32) {
    bf16x8 kf0 = {}, kf1 = {};
    if (quad < 2) {
      int mc0 = m0 + col < LL ? m0 + col : LL - 1;
      int mc1 = m0 + 16 + col < LL ? m0 + 16 + col : LL - 1;
      kf0 = *reinterpret_cast<const bf16x8*>(&kp[mc0 * 16 + quad * 8]);
      kf1 = *reinterpret_cast<const bf16x8*>(&kp[mc1 * 16 + quad * 8]);
    }
    bf16x8 vf;
    {
      int ms = m0 + quad * 8; if (ms > LL - 8) ms = LL - 8;
      vf = *reinterpret_cast<const bf16x8*>(&vp[col * LL + ms]);
    }
    const float4 a4 = *reinterpret_cast<const float4*>(&mb[m0 + quad * 4]);
    const float4 b4 = *reinterpret_cast<const float4*>(&mb[m0 + 16 + quad * 4]);
    float madd[8] = {a4.x, a4.y, a4.z, a4.w, b4.x, b4.y, b4.z, b4.w};
    #pragma unroll
    for (int f = 0; f < 4; f++) {
      f32x4 z = {0.f, 0.f, 0.f, 0.f};
      f32x4 s0 = __builtin_amdgcn_mfma_f32_16x16x32_bf16(kf0, qf[f], z, 0, 0, 0);
      f32x4 s1 = __builtin_amdgcn_mfma_f32_16x16x32_bf16(kf1, qf[f], z, 0, 0, 0);
      float p[8];
      #pragma unroll
      for (int r = 0; r < 4; r++) {
        p[r]     = EXP2F(s0[r] * scale2 + madd[r]);
        p[4 + r] = EXP2F(s1[r] * scale2 + madd[4 + r]);
      }
      float ps = 0.f;
      #pragma unroll
      for (int i = 0; i < 8; i++) ps += p[i];
      psum[f] += ps;
      short* row = &Pl[w][f & 1][col * 40];
      short4 h0 = __builtin_bit_cast(short4, make_uint2(pkbf(p[1], p[0]), pkbf(p[3], p[2])));
      short4 h1 = __builtin_bit_cast(short4, make_uint2(pkbf(p[5], p[4]), pkbf(p[7], p[6])));
      *reinterpret_cast<short4*>(&row[quad * 4])      = h0;
      *reinterpret_cast<short4*>(&row[16 + quad * 4]) = h1;
      bf16x8 pf = *reinterpret_cast<const bf16x8*>(&Pl[w][f & 1][col * 40 + quad * 8]);
      of[f] = __builtin_amdgcn_mfma_f32_16x16x32_bf16(vf, pf, of[f], 0, 0, 0);
    }
  }
  // merge halves: half-1 waves publish partials, half-0 waves combine
  if (half == 1) {
    float* mg = &Mg[pair][lane][0];
    #pragma unroll
    for (int f = 0; f < 4; f++) {
      #pragma unroll
      for (int r = 0; r < 4; r++) mg[f * 4 + r] = of[f][r];
      mg[16 + f] = psum[f];
    }
  }
  __syncthreads();
  if (half == 0 && live) {
    const float* mg = &Mg[pair][lane][0];
    #pragma unroll
    for (int f = 0; f < 4; f++) {
      #pragma unroll
      for (int r = 0; r < 4; r++) of[f][r] += mg[f * 4 + r];
      psum[f] += mg[16 + f];
    }
    #pragma unroll
    for (int f = 0; f < 4; f++) {
      float s = psum[f];
      s += __shfl_xor(s, 16);
      s += __shfl_xor(s, 32);
      float inv = 1.f / s;
      int lf = l0 + f * 16;
      if (lf < LL) {
        #pragma unroll
        for (int r = 0; r < 4; r++)
          ao[base + (size_t)(quad * 4 + r) * LL + lf + col] =
              (unsigned short)f2bf(of[f][r] * inv);
      }
    }
  }
}

// ---------------------------------------------------------------------------
extern "C" void kernel_launch(void* const* d_in, const int* in_sizes, int n_in,
                              void* d_out, int out_size, void* d_ws, size_t ws_size,
                              hipStream_t stream) {
  const float* x    = (const float*)d_in[0];
  const float* mask = (const float*)d_in[1];
  const float* dw_w = (const float*)d_in[2];
  const float* dw_b = (const float*)d_in[3];
  const float* pw_w = (const float*)d_in[4];
  const float* pw_b = (const float*)d_in[5];
  const float* wq   = (const float*)d_in[6];
  const float* bq   = (const float*)d_in[7];
  const float* wk   = (const float*)d_in[8];
  const float* bk   = (const float*)d_in[9];
  const float* wvp  = (const float*)d_in[10];
  const float* bv   = (const float*)d_in[11];
  const float* wo   = (const float*)d_in[12];
  const float* bo   = (const float*)d_in[13];
  const float* fcw  = (const float*)d_in[14];
  const float* fcb  = (const float*)d_in[15];
  const float* lng  = (const float*)d_in[16];
  const float* lnb  = (const float*)d_in[17];
  float* out = (float*)d_out;
  float* ws  = (float*)d_ws;

  float* stats = ws;                                    // 1024 f
  float* pose  = ws + 1024;                             // 51200 f
  float* beff  = pose + 51200;                          // 512 f
  float* maddb = beff + 512;                            // 64*416 f
  unsigned short* wf = (unsigned short*)(maddb + 64 * 416); // 9*16384 bf16
  unsigned short* r0 = wf + 9 * 16384;                  // NBCL bf16 each:
  unsigned short* r1 = r0 + NBCL;
  unsigned short* qt = r1 + NBCL;
  unsigned short* kt = qt + NBCL;
  unsigned short* vbf = kt + NBCL;
  unsigned short* tb = vbf + NBCL;

  prep_kernel<<<882, 256, 0, stream>>>(pw_w, wq, wk, wvp, wo, fcw, pw_b, dw_b,
                                       mask, wf, pose, stats, beff, maddb);
  addpos_stats_kernel<<<3200, 256, 0, stream>>>(x, pose, r0, stats);

  // conv layers, ping-pong r0 <-> r1 (no in-place halo race)
  unsigned short* rin = r0;
  unsigned short* rout = r1;
  for (int i = 0; i < 4; i++) {
    gemmM<2, 1, true, true, true><<<dim3(7, BN), 512, 0, stream>>>(
        wf + i * 16384, rin, beff + i * CC, rin, lng, lnb,
        dw_w + i * CC * KK, stats + i * 128, stats + (i + 1) * 128, rout);
    unsigned short* t = rin; rin = rout; rout = t;
  }
  // after 4 layers: rin = r0 (current residual stream)
  qkv_kernel<<<dim3(7, BN, 3), 512, 0, stream>>>(
      wf, bq, bk, bv, rin, lng, lnb, stats + 4 * 128, qt, kt, vbf);
  attn_kernel<<<dim3(512, 4), 256, 0, stream>>>(qt, kt, vbf, maddb, tb);
  // WO projection + residual -> rout(bf16), stats5
  gemmM<1, 1, false, true, true><<<dim3(7, BN), 512, 0, stream>>>(
      wf + 7 * 16384, tb, bo, rin, nullptr, nullptr, nullptr,
      nullptr, stats + 5 * 128, rout);
  // FC (LN on load) + ReLU + residual -> d_out (fp32)
  gemmM<0, 0, true, true, false><<<dim3(7, BN), 512, 0, stream>>>(
      wf + 8 * 16384, rout, fcb, rout, lng, lnb, nullptr,
      stats + 5 * 128, nullptr, out);
}